// Round 7
// baseline (226.988 us; speedup 1.0000x reference)
//
#include <hip/hip_runtime.h>
#include <hip/hip_cooperative_groups.h>

namespace cg = cooperative_groups;

#define Nn 1024
#define Ee 65536
#define Pq 1024

typedef unsigned long long ull;

struct Params {
    const float* x; const int* ei; const int* pos;
    const float* Wg1; const float* bg1; const float* Wg2; const float* bg2;
    const float* Wm1; const float* bm1; const float* gm1; const float* bem1;
    const float* Wm2; const float* bm2; const float* gm2; const float* bem2;
    const float* Wa; const float* ba; const float* Wb; const float* bb;
    float* out;
    int* degI; int* cursor; ull* Mbit; ull* MTbit; int* csr;
    float* xw1; float* xw2; float* h2;
};

__device__ __forceinline__ float gather_node(const int* __restrict__ csr,
                                             const float* __restrict__ xwsrc,
                                             const int* s_dst, const int* s_deg,
                                             const float* s_dinv, int c, int lane) {
    int s0 = __builtin_amdgcn_readfirstlane(s_dst[c]);
    int n  = __builtin_amdgcn_readfirstlane(s_deg[c]);
    float acc = 0.f;
    int j = s0, end = s0 + n;
    for (; j + 7 < end; j += 8) {
        int r0 = csr[j],     r1 = csr[j + 1], r2 = csr[j + 2], r3 = csr[j + 3];
        int r4 = csr[j + 4], r5 = csr[j + 5], r6 = csr[j + 6], r7 = csr[j + 7];
        float a0 = xwsrc[r0 * 64 + lane] * s_dinv[r0];
        float a1 = xwsrc[r1 * 64 + lane] * s_dinv[r1];
        float a2 = xwsrc[r2 * 64 + lane] * s_dinv[r2];
        float a3 = xwsrc[r3 * 64 + lane] * s_dinv[r3];
        float a4 = xwsrc[r4 * 64 + lane] * s_dinv[r4];
        float a5 = xwsrc[r5 * 64 + lane] * s_dinv[r5];
        float a6 = xwsrc[r6 * 64 + lane] * s_dinv[r6];
        float a7 = xwsrc[r7 * 64 + lane] * s_dinv[r7];
        acc += ((a0 + a1) + (a2 + a3)) + ((a4 + a5) + (a6 + a7));
    }
    for (; j < end; ++j) {
        int r = csr[j];
        acc += xwsrc[r * 64 + lane] * s_dinv[r];
    }
    return acc;
}

__global__ __launch_bounds__(256) void k_mega(Params P) {
    cg::grid_group grid = cg::this_grid();
    __shared__ int   s_dst[Nn];
    __shared__ int   s_deg[Nn];
    __shared__ float s_dinv[Nn];
    __shared__ float s_W[8192];   // Wg1 (P0) -> Wg2 (P3) -> W1|W2 (P4/P5)
    __shared__ int   s_scan[256];

    int tid  = threadIdx.x;
    int lane = tid & 63;
    int wv   = tid >> 6;
    int B    = blockIdx.x;
    int gid  = B * 256 + tid;

    // ---------- phase 0: zero ws buffers + stage Wg1 + xw1 = x @ Wg1 ----------
    if (gid < 1024) { P.degI[gid] = 0; P.cursor[gid] = 0; }
    if (gid < 16384) { P.Mbit[gid] = 0; P.MTbit[gid] = 0; }
    for (int i = tid; i < 8192; i += 256) s_W[i] = P.Wg1[i];
    __syncthreads();
    {
        int r = __builtin_amdgcn_readfirstlane(gid >> 6);
        const float* xr = P.x + r * 128;
        float acc = 0.f;
        #pragma unroll 8
        for (int j = 0; j < 128; ++j) acc = fmaf(xr[j], s_W[j * 64 + lane], acc);
        P.xw1[gid] = acc;
    }
    grid.sync();

    // ---------- phase 1: edge pass (deg + adjacency bitmaps) ----------
    {
        int r = P.ei[gid], c = P.ei[Ee + gid];
        atomicAdd(&P.degI[c], 1);
        atomicOr(&P.Mbit[r * 16 + (c >> 6)], 1ull << (c & 63));
        atomicOr(&P.MTbit[c * 16 + (r >> 6)], 1ull << (r & 63));
    }
    grid.sync();

    // ---------- phase 2: per-block redundant scan + CSR placement ----------
    {
        int d0 = P.degI[4 * tid], d1 = P.degI[4 * tid + 1];
        int d2 = P.degI[4 * tid + 2], d3 = P.degI[4 * tid + 3];
        int sum = d0 + d1 + d2 + d3;
        s_scan[tid] = sum;
        __syncthreads();
        for (int off = 1; off < 256; off <<= 1) {
            int v = (tid >= off) ? s_scan[tid - off] : 0;
            __syncthreads();
            s_scan[tid] += v;
            __syncthreads();
        }
        int base = s_scan[tid] - sum;
        s_dst[4 * tid] = base;
        s_dst[4 * tid + 1] = base + d0;
        s_dst[4 * tid + 2] = base + d0 + d1;
        s_dst[4 * tid + 3] = base + d0 + d1 + d2;
        s_deg[4 * tid] = d0;  s_deg[4 * tid + 1] = d1;
        s_deg[4 * tid + 2] = d2;  s_deg[4 * tid + 3] = d3;
        s_dinv[4 * tid] = rsqrtf((float)d0 + 1.f);
        s_dinv[4 * tid + 1] = rsqrtf((float)d1 + 1.f);
        s_dinv[4 * tid + 2] = rsqrtf((float)d2 + 1.f);
        s_dinv[4 * tid + 3] = rsqrtf((float)d3 + 1.f);
        __syncthreads();
        int r = P.ei[gid], c = P.ei[Ee + gid];
        int slot = atomicAdd(&P.cursor[c], 1);
        P.csr[s_dst[c] + slot] = r;
    }
    grid.sync();

    // ---------- phase 3: gather1 -> h1 (regs) -> fused xw2 = h1 @ Wg2 ----------
    {
        for (int i = tid; i < 4096; i += 256) s_W[i] = P.Wg2[i];
        __syncthreads();
        int c = B * 4 + wv;
        float acc = gather_node(P.csr, P.xw1, s_dst, s_deg, s_dinv, c, lane);
        float dc = s_dinv[c];
        float h1c = dc * acc + dc * dc * P.xw1[c * 64 + lane] + P.bg1[lane];
        float t = 0.f;
        #pragma unroll 8
        for (int j = 0; j < 64; ++j) t = fmaf(__shfl(h1c, j), s_W[j * 64 + lane], t);
        P.xw2[c * 64 + lane] = t;
    }
    grid.sync();

    // ---------- phase 4: stage W1|W2 + gather2 -> h2 ----------
    {
        for (int i = tid; i < 4096; i += 256) {
            s_W[i] = P.Wm1[i];
            s_W[4096 + i] = P.Wm2[i];
        }
        int c = B * 4 + wv;
        float acc = gather_node(P.csr, P.xw2, s_dst, s_deg, s_dinv, c, lane);
        float dc = s_dinv[c];
        P.h2[c * 64 + lane] = dc * acc + dc * dc * P.xw2[c * 64 + lane] + P.bg2[lane];
    }
    grid.sync();

    // ---------- phase 5: bitmap intersect -> on-the-fly edge MLPs -> final MLP ----------
    {
        int p = B * 4 + wv;
        int a = __builtin_amdgcn_readfirstlane(P.pos[p]);
        int b = __builtin_amdgcn_readfirstlane(P.pos[Pq + p]);
        float ha = P.h2[a * 64 + lane], hb = P.h2[b * 64 + lane];
        float lb1 = P.bm1[lane], lg1 = P.gm1[lane], lbe1 = P.bem1[lane];
        float lb2 = P.bm2[lane], lg2 = P.gm2[lane], lbe2 = P.bem2[lane];
        const float* W1s = s_W;
        const float* W2s = s_W + 4096;
        float acc = 0.f;
        for (int wd = 0; wd < 16; ++wd) {
            ull bits = P.Mbit[a * 16 + wd] & P.MTbit[b * 16 + wd];
            while (bits) {
                int k = (wd << 6) + __ffsll(bits) - 1;
                bits &= bits - 1;
                float hk = P.h2[k * 64 + lane];
                float xeA = ha * hk;  // edge (a,k) -> head2 (x2, left operand)
                float xeB = hk * hb;  // edge (k,b) -> head1 (x1, right operand)
                float a2 = lb2, a1 = lb1;
                #pragma unroll 8
                for (int j = 0; j < 64; ++j) {
                    float vA = __shfl(xeA, j);
                    float vB = __shfl(xeB, j);
                    a2 = fmaf(vA, W2s[j * 64 + lane], a2);
                    a1 = fmaf(vB, W1s[j * 64 + lane], a1);
                }
                float s2 = a2, q2 = a2 * a2, s1 = a1, q1 = a1 * a1;
                for (int off = 32; off; off >>= 1) {
                    s2 += __shfl_xor(s2, off); q2 += __shfl_xor(q2, off);
                    s1 += __shfl_xor(s1, off); q1 += __shfl_xor(q1, off);
                }
                float mu2 = s2 * (1.f / 64.f), mu1 = s1 * (1.f / 64.f);
                float v2 = q2 * (1.f / 64.f) - mu2 * mu2;
                float v1 = q1 * (1.f / 64.f) - mu1 * mu1;
                float r2v = rsqrtf(v2 + 1e-5f), r1v = rsqrtf(v1 + 1e-5f);
                float x2v = fmaxf(0.f, (a2 - mu2) * r2v * lg2 + lbe2);
                float x1v = fmaxf(0.f, (a1 - mu1) * r1v * lg1 + lbe1);
                acc += x2v * x1v;
            }
        }
        float xx = ha * hb;
        float t = P.ba[lane];
        #pragma unroll 8
        for (int j = 0; j < 64; ++j) {
            t = fmaf(__shfl(acc, j), P.Wa[j * 64 + lane], t);
            t = fmaf(__shfl(xx, j), P.Wa[(64 + j) * 64 + lane], t);
        }
        t = fmaxf(t, 0.f);
        float v = t * P.Wb[lane];
        for (int off = 32; off; off >>= 1) v += __shfl_xor(v, off);
        if (lane == 0) P.out[p] = v + P.bb[0];
    }
}

extern "C" void kernel_launch(void* const* d_in, const int* in_sizes, int n_in,
                              void* d_out, int out_size, void* d_ws, size_t ws_size,
                              hipStream_t stream) {
    Params p;
    p.x    = (const float*)d_in[0];
    p.ei   = (const int*)d_in[1];
    p.pos  = (const int*)d_in[2];
    p.Wg1  = (const float*)d_in[3];
    p.bg1  = (const float*)d_in[4];
    p.Wg2  = (const float*)d_in[5];
    p.bg2  = (const float*)d_in[6];
    p.Wm1  = (const float*)d_in[7];
    p.bm1  = (const float*)d_in[8];
    p.gm1  = (const float*)d_in[9];
    p.bem1 = (const float*)d_in[10];
    p.Wm2  = (const float*)d_in[11];
    p.bm2  = (const float*)d_in[12];
    p.gm2  = (const float*)d_in[13];
    p.bem2 = (const float*)d_in[14];
    p.Wa   = (const float*)d_in[15];
    p.ba   = (const float*)d_in[16];
    p.Wb   = (const float*)d_in[17];
    p.bb   = (const float*)d_in[18];
    p.out  = (float*)d_out;

    char* w = (char*)d_ws;
    p.degI   = (int*)w;   w += 1024 * 4;
    p.cursor = (int*)w;   w += 1024 * 4;
    p.Mbit   = (ull*)w;   w += 1024 * 16 * 8;
    p.MTbit  = (ull*)w;   w += 1024 * 16 * 8;
    p.csr    = (int*)w;   w += Ee * 4;
    p.xw1    = (float*)w; w += 65536 * 4;
    p.xw2    = (float*)w; w += 65536 * 4;
    p.h2     = (float*)w; w += 65536 * 4;

    void* args[] = {(void*)&p};
    hipLaunchCooperativeKernel((const void*)k_mega, dim3(256), dim3(256), args, 0, stream);
}